// Round 4
// baseline (53.654 us; speedup 1.0000x reference)
//
#include <hip/hip_runtime.h>
#include <math.h>

#define T      600
#define C      14
#define NOUT   500
#define R      4          // batch rows per block
#define WW     64         // time window per GEMM/recurrence phase
#define DSTR   68         // padded t-stride for ds (floats)
#define NW     6          // windows per segment (uniform loop count)
#define SEG1   268        // segment-1 start (32-step warmup before t=300)
#define TMID   300        // record boundary between segments
#define CAP    48         // max events per row per segment

__global__ __launch_bounds__(256, 4)
void snn_v4(const float* __restrict__ x, const float* __restrict__ W1,
            const float* __restrict__ W2, float* __restrict__ out) {
    __shared__ float    ds[2 * R * C * DSTR];   // 30464 B
    __shared__ unsigned evs[2][R][CAP];         // 1536 B, (t<<4)|c
    __shared__ int      ecnt[2][R];

    const int tid = threadIdx.x;
    const int b0  = blockIdx.x * R;
    if (tid < 2 * R) ((int*)ecnt)[tid] = 0;

    const int ss = tid >> 7;                 // segment (0: t<300, 1: t>=268)
    const int rr = (tid >> 5) & (R - 1);     // row 0..3
    const int qq = tid & 31;                 // t-pair within window

    const int wstart = ss ? SEG1 : 0;
    const int tend   = ss ? T    : TMID;
    const int trec   = ss ? TMID : 0;        // record events only at t >= trec

    // recurrence lane mapping (within each 128-thread half)
    const int  cc   = (tid >> 1) & 15;       // channel slot, pair-mirrored
    const int  ce   = (cc < C) ? cc : (C - 1);
    const bool aact = ((tid & 1) == 0) && (cc < C);

    // ---- initial prefetch: window 0 of this segment ----
    float2 xv[C];
    {
        const int t0 = wstart + qq * 2;
        #pragma unroll
        for (int j = 0; j < C; ++j)
            xv[j] = *(const float2*)&x[((long)(b0 + rr) * C + j) * T + t0];
    }
    float v1 = 0.f;

    for (int w = 0; w < NW; ++w) {
        const int tw0  = wstart + w * WW;
        const int wlen = (tend - tw0 < WW) ? (tend - tw0) : WW;   // 64..44/12 or <=0
        __syncthreads();                     // prev recurrence done reading ds

        // ===== GEMM from prefetched regs =====
        if (wlen > 0) {
            #pragma unroll
            for (int c = 0; c < C; ++c) {
                float ax = 0.f, ay = 0.f;
                #pragma unroll
                for (int j = 0; j < C; ++j) {
                    const float wv = 0.5f * W1[c * C + j];   // exact pow2 fold
                    ax = fmaf(xv[j].x, wv, ax);
                    ay = fmaf(xv[j].y, wv, ay);
                }
                *(float2*)&ds[((ss * R + rr) * C + c) * DSTR + qq * 2] =
                    make_float2(ax, ay);
            }
            // prefetch next window (hides under recurrence)
            if (tw0 + WW < tend) {
                const int tn = tw0 + WW + qq * 2;
                if (tn + 1 < T) {
                    #pragma unroll
                    for (int j = 0; j < C; ++j)
                        xv[j] = *(const float2*)&x[((long)(b0 + rr) * C + j) * T + tn];
                }
            }
        }
        __syncthreads();                     // ds ready

        // ===== LIF-1 recurrence: speculative 4-step batches =====
        if (wlen > 0) {
            const float* dp = &ds[((ss * R + rr) * C + ce) * DSTR];
            for (int q = 0; q < wlen; q += 4) {
                const float4 hd = *(const float4*)&dp[q];
                const float a  = fmaf(v1, 0.5f, hd.x);
                const float b  = fmaf(a,  0.5f, hd.y);
                const float c2 = fmaf(b,  0.5f, hd.z);
                const float d  = fmaf(c2, 0.5f, hd.w);
                const float m  = fmaxf(fmaxf(a, b), fmaxf(c2, d));
                if (__builtin_expect(__ballot(m >= 7.0f) != 0ull, 0)) {
                    float vv = v1;           // exact slow path
                    #pragma unroll
                    for (int u = 0; u < 4; ++u) {
                        const float h = (u == 0) ? hd.x : (u == 1) ? hd.y
                                      : (u == 2) ? hd.z : hd.w;
                        vv = fmaf(vv, 0.5f, h);
                        if (vv >= 7.0f) {
                            vv = 0.5f;       // reset + exact feedback fold
                            const int t = tw0 + q + u;
                            if (aact && t >= trec) {
                                const int idx = atomicAdd(&ecnt[ss][rr], 1);
                                if (idx < CAP)
                                    evs[ss][rr][idx] =
                                        ((unsigned)t << 4) | (unsigned)cc;
                            }
                        }
                    }
                    v1 = vv;
                } else {
                    v1 = d;                  // no spike: bitwise exact
                }
            }
        }
    }
    __syncthreads();                         // evs/ecnt complete

    // ===== event-driven LIF-2 + exp: half ss does outputs k=8*ss..8*ss+7 =====
    const int lane = tid & 31;
    float v2[8];
    #pragma unroll
    for (int k = 0; k < 8; ++k) v2[k] = 0.f;
    int tprev = -1;

    #pragma unroll
    for (int L = 0; L < 2; ++L) {            // seg0 events (t<300), then seg1
        const int n = min(ecnt[L][rr], CAP);
        const unsigned* ev = &evs[L][rr][0];
        int e = 0;
        while (e < n) {
            const int t = (int)(ev[e] >> 4);
            float i2[8];
            #pragma unroll
            for (int k = 0; k < 8; ++k) i2[k] = 0.f;
            do {                             // merge all channels firing at t
                const int c = (int)(ev[e] & 15);
                #pragma unroll
                for (int k = 0; k < 8; ++k) {
                    const int o = lane + ((k + 8 * ss) << 5);
                    if (o < NOUT) i2[k] += W2[o * C + c];
                }
                ++e;
            } while (e < n && (int)(ev[e] >> 4) == t);

            const int gap = t - tprev - 1;
            if (gap > 0) {
                #pragma unroll
                for (int k = 0; k < 8; ++k) v2[k] = ldexpf(v2[k], -gap);
            }
            #pragma unroll
            for (int k = 0; k < 8; ++k) {
                const float v = v2[k] + (i2[k] - v2[k]) * 0.5f;  // ref order
                v2[k] = (v >= 7.0f) ? 0.f : v;                   // hard reset
            }
            tprev = t;
        }
    }
    {
        const int gap = (T - 1) - tprev;
        if (gap > 0) {
            #pragma unroll
            for (int k = 0; k < 8; ++k) v2[k] = ldexpf(v2[k], -gap);
        }
    }
    #pragma unroll
    for (int k = 0; k < 8; ++k) {
        const int o = lane + ((k + 8 * ss) << 5);
        if (o < NOUT) out[(long)(b0 + rr) * NOUT + o] = expf(v2[k]);
    }
}

extern "C" void kernel_launch(void* const* d_in, const int* in_sizes, int n_in,
                              void* d_out, int out_size, void* d_ws, size_t ws_size,
                              hipStream_t stream) {
    const float* x  = (const float*)d_in[0];
    const float* W1 = (const float*)d_in[1];
    const float* W2 = (const float*)d_in[2];
    float* o = (float*)d_out;
    const int B = in_sizes[0] / (C * T);     // 4096
    snn_v4<<<B / R, 256, 0, stream>>>(x, W1, W2, o);
}

// Round 5
// 49.151 us; speedup vs baseline: 1.0916x; 1.0916x over previous
//
#include <hip/hip_runtime.h>
#include <math.h>

#define T     600
#define C     14
#define NOUT  500
#define W     128        // time window per GEMM/chain phase
#define DSTR  132        // padded t-stride (floats); rows 0..13 = D/2, row 14 = zeros
#define CAP   64         // max (t,mask) events per row

__global__ __launch_bounds__(64, 4)
void snn_v5(const float* __restrict__ x, const float* __restrict__ W1,
            const float* __restrict__ W2, float* __restrict__ out) {
    __shared__ float    ds[15 * DSTR];     // 7920 B
    __shared__ unsigned evs[CAP];          // (t<<14) | 14-bit channel mask
    __shared__ int      ecnt;

    const int  lane = threadIdx.x;
    const long row  = blockIdx.x;
    const float* xr = &x[row * (long)(C * T)];

    if (lane == 0) ecnt = 0;
    for (int i = lane; i < DSTR; i += 64) ds[14 * DSTR + i] = 0.f;  // zero pad row

    const int ce = (lane < C) ? lane : 14;   // chain source row (14 => stays 0)
    float v1 = 0.f;

    for (int t0 = 0; t0 < T; t0 += W) {
        const int wlen = (T - t0 < W) ? (T - t0) : W;   // 128,128,128,128,88
        __syncthreads();                     // prev chain done reading ds

        // ===== GEMM: lane owns t-pair (t0 + 2*lane) =====
        if (2 * lane < wlen) {
            const int tt = t0 + 2 * lane;
            float2 xv[C];
            #pragma unroll
            for (int j = 0; j < C; ++j)
                xv[j] = *(const float2*)&xr[j * T + tt];
            #pragma unroll
            for (int c = 0; c < C; ++c) {
                float ax = 0.f, ay = 0.f;
                #pragma unroll
                for (int j = 0; j < C; ++j) {
                    const float wv = 0.5f * W1[c * C + j];   // exact pow2 fold
                    ax = fmaf(xv[j].x, wv, ax);
                    ay = fmaf(xv[j].y, wv, ay);
                }
                *(float2*)&ds[c * DSTR + 2 * lane] = make_float2(ax, ay);
            }
        }
        __syncthreads();                     // ds ready

        // ===== LIF-1 chain: speculative 4-step batches =====
        const float* dp = &ds[ce * DSTR];
        for (int q = 0; q < wlen; q += 4) {
            const float4 hd = *(const float4*)&dp[q];
            const float a  = fmaf(v1, 0.5f, hd.x);
            const float b  = fmaf(a,  0.5f, hd.y);
            const float c2 = fmaf(b,  0.5f, hd.z);
            const float d  = fmaf(c2, 0.5f, hd.w);
            const float m  = fmaxf(fmaxf(a, b), fmaxf(c2, d));
            if (__builtin_expect(__ballot(m >= 7.0f) != 0ull, 0)) {
                float vv = v1;               // exact slow path (rare, wave-uniform)
                #pragma unroll
                for (int u = 0; u < 4; ++u) {
                    const float h = (u == 0) ? hd.x : (u == 1) ? hd.y
                                  : (u == 2) ? hd.z : hd.w;
                    vv = fmaf(vv, 0.5f, h);
                    const unsigned mk = (unsigned)__ballot(vv >= 7.0f) & 0x3FFFu;
                    if (mk) {
                        if (vv >= 7.0f) vv = 0.5f;   // reset + exact feedback fold
                        if (lane == 0 && ecnt < CAP)
                            evs[ecnt++] = ((unsigned)(t0 + q + u) << 14) | mk;
                    }
                }
                v1 = vv;
            } else {
                v1 = d;                      // no spike in batch: bitwise exact
            }
        }
    }
    __syncthreads();                         // evs/ecnt final

    // ===== event-driven LIF-2 + exp: 64 lanes x 8 outputs =====
    const int n = (ecnt < CAP) ? ecnt : CAP;
    float v2[8];
    #pragma unroll
    for (int k = 0; k < 8; ++k) v2[k] = 0.f;
    int tprev = -1;

    for (int e = 0; e < n; ++e) {
        const unsigned ev = evs[e];
        const int t = (int)(ev >> 14);
        unsigned mm = ev & 0x3FFFu;
        float i2[8];
        #pragma unroll
        for (int k = 0; k < 8; ++k) i2[k] = 0.f;
        while (mm) {                         // sum active W2 columns
            const int c = (int)__builtin_ctz(mm);
            mm &= mm - 1;
            #pragma unroll
            for (int k = 0; k < 8; ++k) {
                const int o = lane + (k << 6);
                if (o < NOUT) i2[k] += W2[o * C + c];
            }
        }
        const int gap = t - tprev - 1;
        if (gap > 0) {                       // exact pure-decay run
            #pragma unroll
            for (int k = 0; k < 8; ++k) v2[k] = ldexpf(v2[k], -gap);
        }
        #pragma unroll
        for (int k = 0; k < 8; ++k) {
            const float v = v2[k] + (i2[k] - v2[k]) * 0.5f;   // ref-order charge
            v2[k] = (v >= 7.0f) ? 0.f : v;                    // hard reset
        }
        tprev = t;
    }
    {
        const int gap = (T - 1) - tprev;
        if (gap > 0) {
            #pragma unroll
            for (int k = 0; k < 8; ++k) v2[k] = ldexpf(v2[k], -gap);
        }
    }
    #pragma unroll
    for (int k = 0; k < 8; ++k) {
        const int o = lane + (k << 6);
        if (o < NOUT) out[row * NOUT + o] = expf(v2[k]);
    }
}

extern "C" void kernel_launch(void* const* d_in, const int* in_sizes, int n_in,
                              void* d_out, int out_size, void* d_ws, size_t ws_size,
                              hipStream_t stream) {
    const float* x  = (const float*)d_in[0];
    const float* W1 = (const float*)d_in[1];
    const float* W2 = (const float*)d_in[2];
    float* o = (float*)d_out;
    const int B = in_sizes[0] / (C * T);     // 4096
    snn_v5<<<B, 64, 0, stream>>>(x, W1, W2, o);
}